// Round 6
// baseline (188.812 us; speedup 1.0000x reference)
//
#include <hip/hip_runtime.h>
#include <cstdint>
#include <cstddef>

typedef int   v4i __attribute__((ext_vector_type(4)));
typedef float v4f __attribute__((ext_vector_type(4)));
typedef unsigned int u32;

constexpr int B_   = 64;
constexpr int CIN  = 96;
constexpr int P_   = 784;     // 28*28
constexpr int CMID = 576;
constexpr int COUT = 96;
constexpr int NOUT = B_ * COUT * P_;
constexpr float NBITF = 127.0f;
constexpr float EPSF  = 1e-5f;
constexpr float MAGICF = 12582912.0f;    // 1.5 * 2^23
constexpr int   BIASI  = 0x4B400000;     // float bits of MAGICF (low byte 0)

// x8t D-layout: dword [b][pt13][kdw][pxl64] = k-bytes 4kdw..+3 of px pt*64+pxl
//   kdw 0..23 = ic 0..95, 24..31 = zero (K pad 96->128), 32..35 slack
constexpr int XKD = 36;
constexpr int XBD = 13 * XKD * 64;   // dwords per batch (29952)
// y2px: plain [b][ch 576][196 dwords] px-packed int8 levels

__device__ __forceinline__ int dot3(u32 a, u32 w, int acc) {
#if __has_builtin(__builtin_amdgcn_sdot4)
    return __builtin_amdgcn_sdot4((int)a, (int)w, acc, false);
#else
    return acc + (int)(signed char)(a)        * (int)(signed char)(w)
               + (int)(signed char)(a >> 8)   * (int)(signed char)(w >> 8)
               + (int)(signed char)(a >> 16)  * (int)(signed char)(w >> 16);
#endif
}

__device__ __forceinline__ void tr4(u32 S0, u32 S1, u32 S2, u32 S3, u32 O[4]) {
    u32 u01 = __builtin_amdgcn_perm(S1, S0, 0x05010400u);
    u32 u23 = __builtin_amdgcn_perm(S3, S2, 0x05010400u);
    u32 v01 = __builtin_amdgcn_perm(S1, S0, 0x07030602u);
    u32 v23 = __builtin_amdgcn_perm(S3, S2, 0x07030602u);
    O[0] = __builtin_amdgcn_perm(u23, u01, 0x05040100u);
    O[1] = __builtin_amdgcn_perm(u23, u01, 0x07060302u);
    O[2] = __builtin_amdgcn_perm(v23, v01, 0x05040100u);
    O[3] = __builtin_amdgcn_perm(v23, v01, 0x07060302u);
}

// pack low byte of 4 dwords into one dword
__device__ __forceinline__ u32 pack4(u32 t0, u32 t1, u32 t2, u32 t3) {
    u32 p01 = __builtin_amdgcn_perm(t1, t0, 0x05010400u);
    u32 p23 = __builtin_amdgcn_perm(t3, t2, 0x05010400u);
    return __builtin_amdgcn_perm(p23, p01, 0x05040100u);
}

// ---------------------------------------------------------------------------
// prep_all: blocks [0,448) = quant_x (pt 0..6 x b 0..63); blocks [448,760) =
// weight prep, 4 single-wave jobs per block (1248 jobs).
// ---------------------------------------------------------------------------
__global__ __launch_bounds__(256)
void prep_all(const float* __restrict__ x,
              const float* __restrict__ w1, const float* __restrict__ g1,
              const float* __restrict__ b1, const float* __restrict__ m1,
              const float* __restrict__ v1,
              const float* __restrict__ w2, const float* __restrict__ g2,
              const float* __restrict__ b2, const float* __restrict__ m2,
              const float* __restrict__ v2,
              const float* __restrict__ w3, const float* __restrict__ g3,
              const float* __restrict__ b3, const float* __restrict__ m3,
              const float* __restrict__ v3,
              const float* __restrict__ r0, const int* __restrict__ cluster,
              u32* __restrict__ x8t,
              int8_t* __restrict__ w1qp, float* __restrict__ ws1, float* __restrict__ bf1,
              v4i* __restrict__ w2pk, float* __restrict__ ws2, float* __restrict__ bf2,
              int8_t* __restrict__ w3qp, float* __restrict__ ws3, float* __restrict__ bf3)
{
    __shared__ u32 T[112 * 37];
    int tid = threadIdx.x;

    if (blockIdx.x < 448) {
        // ---------------- quant_x ----------------
        int pt0 = blockIdx.x % 7, b = blockIdx.x / 7;
        float inv_s0 = NBITF / r0[cluster[0]];

        for (int i = tid; i < 112 * 12; i += 256) {
            int row = i / 12, cpad = i - row * 12;
            T[row * 37 + 24 + cpad] = 0u;
        }
        for (int u = tid; u < 24 * 28; u += 256) {
            int pq = u % 28, icq = u / 28;
            int pxb = pt0 * 112 + pq * 4;
            int q[4][4];
            #pragma unroll
            for (int j = 0; j < 4; j++) {
                v4f xv = *(const v4f*)(x + ((size_t)b * CIN + icq * 4 + j) * P_ + pxb);
                #pragma unroll
                for (int i = 0; i < 4; i++)
                    q[j][i] = (int)fminf(fmaxf(rintf(xv[i] * inv_s0), -127.f), 127.f);
            }
            #pragma unroll
            for (int i = 0; i < 4; i++) {
                u32 t0 = __builtin_amdgcn_perm((u32)q[1][i], (u32)q[0][i], 0x00000400u);
                u32 t1 = __builtin_amdgcn_perm((u32)q[3][i], (u32)q[2][i], 0x00000400u);
                T[(pq * 4 + i) * 37 + icq] = __builtin_amdgcn_perm(t1, t0, 0x05040100u);
            }
        }
        __syncthreads();
        u32* gb = x8t + (size_t)b * XBD;
        for (int i = tid; i < XKD * 112; i += 256) {
            int icq = i / 112, pxo = i - icq * 112;
            int px = pt0 * 112 + pxo;
            gb[(((px >> 6) * XKD) + icq) * 64 + (px & 63)] = T[pxo * 37 + icq];
        }
        return;
    }

    // ---------------- weight prep: 4 wave-jobs per block ----------------
    int lane = tid & 63, wv = tid >> 6;
    int blk = (blockIdx.x - 448) * 4 + wv;   // 0..1247

    const float *w, *g, *bb, *mm, *vv;
    int oc, K, which;
    if (blk < CMID)            { which = 0; w = w1; g = g1; bb = b1; mm = m1; vv = v1; oc = blk;            K = CIN;  }
    else if (blk < 2 * CMID)   { which = 1; w = w2; g = g2; bb = b2; mm = m2; vv = v2; oc = blk - CMID;     K = 9;    }
    else                       { which = 2; w = w3; g = g3; bb = b3; mm = m3; vv = v3; oc = blk - 2 * CMID; K = CMID; }

    float scale = g[oc] / sqrtf(vv[oc] + EPSF);

    float mx = 0.f;
    for (int k = lane; k < K; k += 64)
        mx = fmaxf(mx, fabsf(w[oc * K + k] * scale));
    #pragma unroll
    for (int off = 1; off < 64; off <<= 1)
        mx = fmaxf(mx, __shfl_xor(mx, off));

    float s = mx / NBITF;

    int myq = 0;
    for (int k = lane; k < K; k += 64) {
        float wf = w[oc * K + k] * scale;
        float q  = fminf(fmaxf(rintf(wf / s), -127.f), 127.f);
        if (which == 0)      w1qp[oc * 144 + k] = (int8_t)q;
        else if (which == 1) myq = (int)q;
        else                 w3qp[oc * 592 + k] = (int8_t)q;
    }
    if (which == 0 && lane < 12)
        ((u32*)(w1qp + oc * 144))[24 + lane] = 0u;
    if (which == 1) {
        u32 qq[9];
        #pragma unroll
        for (int t = 0; t < 9; t++) qq[t] = (u32)__shfl(myq, t, 64) & 0xffu;
        if (lane == 0) {
            v4i pk;
            pk[0] = (int)(qq[0] | (qq[1] << 8) | (qq[2] << 16));
            pk[1] = (int)(qq[3] | (qq[4] << 8) | (qq[5] << 16));
            pk[2] = (int)(qq[6] | (qq[7] << 8) | (qq[8] << 16));
            pk[3] = 0;
            w2pk[oc] = pk;
        }
    }
    if (lane == 0) {
        float bf = bb[oc] - mm[oc] * scale;
        if (which == 0)      { ws1[oc] = s; bf1[oc] = bf; }
        else if (which == 1) { ws2[oc] = s; bf2[oc] = bf; }
        else                 { ws3[oc] = s; bf3[oc] = bf; }
    }
}

// ---------------------------------------------------------------------------
// conv12v2: fused conv1 (swapped-operand int8 MFMA over a 128-px window:
// 64 out px + halo) + ReLU6 quant into LDS + 3x3 depthwise from LDS +
// ReLU6 quant -> y2px global. One barrier. LDS 26.1 KB.
// Grid (3 mt x 13 pt, 64 b); block 256 = 4 waves x 48 oc.
// ---------------------------------------------------------------------------
__global__ __launch_bounds__(256)
void conv12v2(const u32* __restrict__ x8t, const int8_t* __restrict__ w1qp,
              const float* __restrict__ ws1, const float* __restrict__ bf1,
              const v4i* __restrict__ w2pk, const float* __restrict__ ws2,
              const float* __restrict__ bf2,
              const float* __restrict__ r0, const float* __restrict__ r1,
              const float* __restrict__ r2, const int* __restrict__ cluster,
              u32* __restrict__ y2px)
{
    __shared__ u32 y1w[192 * 34];   // [chl][34dw]: 32 window-dwords + 2 pad

    int tid = threadIdx.x, b = blockIdx.y;
    int mt = blockIdx.x % 3, pt = blockIdx.x / 3;
    int p0 = pt * 64;
    int lane = tid & 63, wv = tid >> 6;
    int n = lane & 15, q4 = lane >> 4;
    int ocw = mt * 192 + wv * 48;

    int   c      = cluster[0];
    float s0     = r0[c] / NBITF;
    float s1     = r1[c] / NBITF;
    float inv_s1 = NBITF / r1[c];
    float inv_s2 = NBITF / r2[c];
    int   u1i    = (int)fminf(rintf(6.f * inv_s1), 127.f);
    int   u2i    = (int)fminf(rintf(6.f * inv_s2), 127.f);

    // ---- conv1 MFMA over window px [p0-32, p0+96) ----
    const u32* xb = x8t + (size_t)b * XBD;
    int abase[8];
    #pragma unroll
    for (int jm = 0; jm < 8; jm++) {
        int px = p0 - 32 + 16 * jm + n;
        px = min(max(px, 0), P_ - 1);
        abase[jm] = ((px >> 6) * XKD) * 64 + (px & 63);
    }

    v4i acc[3][8];
    #pragma unroll
    for (int jn = 0; jn < 3; jn++)
        #pragma unroll
        for (int jm = 0; jm < 8; jm++) acc[jn][jm] = (v4i){0, 0, 0, 0};

    const v4i* w4 = (const v4i*)w1qp;   // 9 v4i per oc
    #pragma unroll
    for (int ks = 0; ks < 2; ks++) {
        v4i bfr[3];
        #pragma unroll
        for (int jn = 0; jn < 3; jn++) {
            int oc = ocw + 16 * jn + n;
            bfr[jn] = w4[oc * 9 + ks * 4 + q4];
        }
        int kb = (16 * ks + 4 * q4) * 64;
        #pragma unroll
        for (int jm = 0; jm < 8; jm++) {
            u32 d0 = xb[abase[jm] + kb];
            u32 d1 = xb[abase[jm] + kb + 64];
            u32 d2 = xb[abase[jm] + kb + 128];
            u32 d3 = xb[abase[jm] + kb + 192];
            v4i afr = (v4i){(int)d0, (int)d1, (int)d2, (int)d3};
            #pragma unroll
            for (int jn = 0; jn < 3; jn++)
                acc[jn][jm] = __builtin_amdgcn_mfma_i32_16x16x64_i8(afr, bfr[jn], acc[jn][jm], 0, 0, 0);
        }
    }

    // ---- epilogue 1: quant(relu6) -> px-packed dwords in LDS ----
    #pragma unroll
    for (int jn = 0; jn < 3; jn++) {
        int   oc  = ocw + 16 * jn + n;
        int   chl = wv * 48 + 16 * jn + n;
        float scv = s0 * ws1[oc] * inv_s1;
        float bbv = bf1[oc] * inv_s1;
        #pragma unroll
        for (int jm = 0; jm < 8; jm++) {
            u32 t[4];
            #pragma unroll
            for (int r = 0; r < 4; r++) {
                int wpx = p0 - 32 + 16 * jm + 4 * q4 + r;
                float f = fmaf((float)acc[jn][jm][r], scv, bbv) + MAGICF;
                int v = min(max(__float_as_int(f), BIASI), BIASI + u1i);
                t[r] = ((unsigned)wpx < (unsigned)P_) ? (u32)v : (u32)BIASI;
            }
            y1w[chl * 34 + 4 * jm + q4] = pack4(t[0], t[1], t[2], t[3]);
        }
    }
    __syncthreads();

    // ---- depthwise 3x3 from LDS; out px [p0, p0+64) ----
    int d0g = p0 >> 2;
    #pragma unroll
    for (int it = 0; it < 12; it++) {
        int u   = tid + 256 * it;      // < 3072
        int chl = u >> 4, dq = u & 15;
        int d   = d0g + dq;            // global out dword (196/ch)
        int gcol = d % 7;
        int base = chl * 34 + 8 + dq;

        u32 M[3][3];
        #pragma unroll
        for (int rr = 0; rr < 3; rr++) {
            int o = (rr - 1) * 7;
            M[rr][0] = (gcol == 0) ? 0u : y1w[base + o - 1];
            M[rr][1] = y1w[base + o];
            M[rr][2] = (gcol == 6) ? 0u : y1w[base + o + 1];
        }
        int ch = mt * 192 + chl;
        v4i wpk = w2pk[ch];
        int a0 = 0, a1 = 0, a2 = 0, a3 = 0;
        #pragma unroll
        for (int rr = 0; rr < 3; rr++) {
            u32 Dm1 = M[rr][0], D = M[rr][1], Dp1 = M[rr][2];
            u32 pk = (u32)((rr == 0) ? wpk[0] : (rr == 1) ? wpk[1] : wpk[2]);
            a0 = dot3(__builtin_amdgcn_alignbyte(D, Dm1, 3), pk, a0);
            a1 = dot3(D, pk, a1);
            a2 = dot3(__builtin_amdgcn_alignbyte(Dp1, D, 1), pk, a2);
            a3 = dot3(__builtin_amdgcn_alignbyte(Dp1, D, 2), pk, a3);
        }
        float scv = s1 * ws2[ch] * inv_s2;
        float bbv = bf2[ch] * inv_s2;
        int aa[4] = {a0, a1, a2, a3};
        u32 tq[4];
        #pragma unroll
        for (int i = 0; i < 4; i++) {
            float f = fmaf((float)aa[i], scv, bbv) + MAGICF;
            tq[i] = (u32)min(max(__float_as_int(f), BIASI), BIASI + u2i);
        }
        if (d < 196)
            y2px[(size_t)(b * CMID + ch) * 196 + d] = pack4(tq[0], tq[1], tq[2], tq[3]);
    }
}

// ---------------------------------------------------------------------------
// conv3s: 1x1 projection 576->96. One LDS bounce transposes y2 px-packed ->
// ch-packed (tr4); A (w3) frags from L2; fused residual + requant + s3.
// Block 256 = 4 waves x 16 px; grid (13 pt, 64 b). LDS 38.6 KB.
// ---------------------------------------------------------------------------
__global__ __launch_bounds__(256)
void conv3s(const u32* __restrict__ y2px, const int8_t* __restrict__ w3qp,
            const float* __restrict__ ws3, const float* __restrict__ bf3,
            const float* __restrict__ x, const float* __restrict__ r2,
            const float* __restrict__ r3, const int* __restrict__ cluster,
            float* __restrict__ out)
{
    __shared__ u32 Bsh[144 * 67];

    int tid = threadIdx.x, b = blockIdx.y, pt = blockIdx.x;
    int p0d = pt * 16;

    int   c      = cluster[0];
    float s2     = r2[c] / NBITF;
    float s3     = r3[c] / NBITF;
    float inv_s3 = NBITF / r3[c];

    for (int u = tid; u < 2304; u += 256) {
        int pxq = u & 15, chq = u >> 4;
        u32 S[4];
        #pragma unroll
        for (int r = 0; r < 4; r++) {
            int col = min(p0d + pxq, 195);
            S[r] = y2px[(size_t)(b * CMID + 4 * chq + r) * 196 + col];
        }
        u32 O[4];
        tr4(S[0], S[1], S[2], S[3], O);
        #pragma unroll
        for (int k = 0; k < 4; k++)
            Bsh[chq * 67 + 4 * pxq + k] = O[k];
    }
    __syncthreads();

    int lane = tid & 63, wv = tid >> 6;
    int n = lane & 15, q4 = lane >> 4;
    int pxl = wv * 16 + n;

    v4i acc[6];
    #pragma unroll
    for (int i = 0; i < 6; i++) acc[i] = (v4i){0, 0, 0, 0};

    #pragma unroll
    for (int ks = 0; ks < 9; ks++) {
        int kr = 16 * ks + 4 * q4;
        u32 b0 = Bsh[(kr + 0) * 67 + pxl];
        u32 b1 = Bsh[(kr + 1) * 67 + pxl];
        u32 b2 = Bsh[(kr + 2) * 67 + pxl];
        u32 b3 = Bsh[(kr + 3) * 67 + pxl];
        v4i bfr = (v4i){(int)b0, (int)b1, (int)b2, (int)b3};
        #pragma unroll
        for (int i = 0; i < 6; i++) {
            v4i afr = *(const v4i*)(w3qp + (size_t)(i * 16 + n) * 592 + ks * 64 + q4 * 16);
            acc[i] = __builtin_amdgcn_mfma_i32_16x16x64_i8(afr, bfr, acc[i], 0, 0, 0);
        }
    }

    int px = pt * 64 + pxl;
    if (px < P_) {
        #pragma unroll
        for (int i = 0; i < 6; i++) {
            #pragma unroll
            for (int r = 0; r < 4; r++) {
                int oc = i * 16 + q4 * 4 + r;
                size_t gi = (size_t)(b * COUT + oc) * P_ + px;
                float v  = (float)acc[i][r] * (s2 * ws3[oc]) + bf3[oc] + x[gi];
                float f  = fmaf(v, inv_s3, MAGICF);
                int lvl  = min(max(__float_as_int(f) - BIASI, -127), 127);
                out[gi]  = (float)lvl * s3;
            }
        }
    }
    if (pt == 0 && b == 0 && tid == 0)
        out[NOUT] = s3;
}

// ---------------------------------------------------------------------------
extern "C" void kernel_launch(void* const* d_in, const int* in_sizes, int n_in,
                              void* d_out, int out_size, void* d_ws, size_t ws_size,
                              hipStream_t stream)
{
    const float* x  = (const float*)d_in[0];
    const float* w1 = (const float*)d_in[1];
    const float* g1 = (const float*)d_in[2];
    const float* b1 = (const float*)d_in[3];
    const float* m1 = (const float*)d_in[4];
    const float* v1 = (const float*)d_in[5];
    const float* w2 = (const float*)d_in[6];
    const float* g2 = (const float*)d_in[7];
    const float* b2 = (const float*)d_in[8];
    const float* m2 = (const float*)d_in[9];
    const float* v2 = (const float*)d_in[10];
    const float* w3 = (const float*)d_in[11];
    const float* g3 = (const float*)d_in[12];
    const float* b3 = (const float*)d_in[13];
    const float* m3 = (const float*)d_in[14];
    const float* v3 = (const float*)d_in[15];
    const float* r0 = (const float*)d_in[16];
    const float* r1 = (const float*)d_in[17];
    const float* r2 = (const float*)d_in[18];
    const float* r3 = (const float*)d_in[19];
    const int*   cl = (const int*)d_in[20];

    float* out = (float*)d_out;

    char*  ws  = (char*)d_ws;
    size_t off = 0;
    auto carve = [&](size_t bytes) {
        size_t cur = off;
        off = (off + bytes + 255) & ~(size_t)255;
        return (void*)(ws + cur);
    };
    int8_t* w1qp = (int8_t*)carve((size_t)CMID * 144);
    float*  ws1  = (float*)carve(CMID * 4);
    float*  bf1  = (float*)carve(CMID * 4);
    v4i*    w2pk = (v4i*)carve((size_t)CMID * 16);
    float*  ws2  = (float*)carve(CMID * 4);
    float*  bf2  = (float*)carve(CMID * 4);
    int8_t* w3qp = (int8_t*)carve((size_t)COUT * 592);
    float*  ws3  = (float*)carve(COUT * 4);
    float*  bf3  = (float*)carve(COUT * 4);
    u32*    x8t  = (u32*)carve((size_t)B_ * XBD * 4);          // 7.7 MB
    u32*    y2px = (u32*)carve((size_t)B_ * CMID * 196 * 4);   // 28.9 MB
    (void)ws_size; (void)in_sizes; (void)n_in; (void)out_size;

    prep_all<<<dim3(760), dim3(256), 0, stream>>>(
        x, w1, g1, b1, m1, v1, w2, g2, b2, m2, v2, w3, g3, b3, m3, v3,
        r0, cl, x8t,
        w1qp, ws1, bf1, w2pk, ws2, bf2, w3qp, ws3, bf3);

    conv12v2<<<dim3(39, B_), dim3(256), 0, stream>>>(
        x8t, w1qp, ws1, bf1, w2pk, ws2, bf2, r0, r1, r2, cl, y2px);

    conv3s<<<dim3(13, B_), dim3(256), 0, stream>>>(
        y2px, w3qp, ws3, bf3, x, r2, r3, cl, out);
}

// Round 7
// 177.605 us; speedup vs baseline: 1.0631x; 1.0631x over previous
//
#include <hip/hip_runtime.h>
#include <cstdint>
#include <cstddef>

typedef int   v4i __attribute__((ext_vector_type(4)));
typedef float v4f __attribute__((ext_vector_type(4)));
typedef unsigned int u32;

constexpr int B_   = 64;
constexpr int CIN  = 96;
constexpr int P_   = 784;     // 28*28
constexpr int CMID = 576;
constexpr int COUT = 96;
constexpr int NOUT = B_ * COUT * P_;
constexpr float NBITF = 127.0f;
constexpr float EPSF  = 1e-5f;
constexpr float MAGICF = 12582912.0f;    // 1.5 * 2^23
constexpr int   BIASI  = 0x4B400000;     // float bits of MAGICF (low byte 0)

// x8t2: v4i X[b][pt 13][g 8][pxl 64] = k-bytes 16g..16g+15 of px pt*64+pxl
//   (g 0..5 = ic 0..95, g 6..7 = zero K-pad 96->128). One MFMA A-frag = 1 v4i.
constexpr int XB4 = 13 * 8 * 64;        // v4i per batch (6656)
// y2t:  v4i Y[b][pt 13][kg 36][pxl 64] = ch-bytes 16kg..16kg+15 at px.
constexpr int YB4 = 13 * 36 * 64;       // v4i per batch (29952)

__device__ __forceinline__ int dot3(u32 a, u32 w, int acc) {
#if __has_builtin(__builtin_amdgcn_sdot4)
    return __builtin_amdgcn_sdot4((int)a, (int)w, acc, false);
#else
    return acc + (int)(signed char)(a)        * (int)(signed char)(w)
               + (int)(signed char)(a >> 8)   * (int)(signed char)(w >> 8)
               + (int)(signed char)(a >> 16)  * (int)(signed char)(w >> 16);
#endif
}

__device__ __forceinline__ void tr4(u32 S0, u32 S1, u32 S2, u32 S3, u32 O[4]) {
    u32 u01 = __builtin_amdgcn_perm(S1, S0, 0x05010400u);
    u32 u23 = __builtin_amdgcn_perm(S3, S2, 0x05010400u);
    u32 v01 = __builtin_amdgcn_perm(S1, S0, 0x07030602u);
    u32 v23 = __builtin_amdgcn_perm(S3, S2, 0x07030602u);
    O[0] = __builtin_amdgcn_perm(u23, u01, 0x05040100u);
    O[1] = __builtin_amdgcn_perm(u23, u01, 0x07060302u);
    O[2] = __builtin_amdgcn_perm(v23, v01, 0x05040100u);
    O[3] = __builtin_amdgcn_perm(v23, v01, 0x07060302u);
}

__device__ __forceinline__ u32 pack4(u32 t0, u32 t1, u32 t2, u32 t3) {
    u32 p01 = __builtin_amdgcn_perm(t1, t0, 0x05010400u);
    u32 p23 = __builtin_amdgcn_perm(t3, t2, 0x05010400u);
    return __builtin_amdgcn_perm(p23, p01, 0x05040100u);
}

// ---------------------------------------------------------------------------
// prep_all: blocks [0,448) = quant_x into x8t2; blocks [448,760) = weight
// prep (4 single-wave jobs per block).
// ---------------------------------------------------------------------------
__global__ __launch_bounds__(256)
void prep_all(const float* __restrict__ x,
              const float* __restrict__ w1, const float* __restrict__ g1,
              const float* __restrict__ b1, const float* __restrict__ m1,
              const float* __restrict__ v1,
              const float* __restrict__ w2, const float* __restrict__ g2,
              const float* __restrict__ b2, const float* __restrict__ m2,
              const float* __restrict__ v2,
              const float* __restrict__ w3, const float* __restrict__ g3,
              const float* __restrict__ b3, const float* __restrict__ m3,
              const float* __restrict__ v3,
              const float* __restrict__ r0, const int* __restrict__ cluster,
              u32* __restrict__ x8t2,
              int8_t* __restrict__ w1qp, float* __restrict__ ws1, float* __restrict__ bf1,
              v4i* __restrict__ w2pk, float* __restrict__ ws2, float* __restrict__ bf2,
              int8_t* __restrict__ w3qp, float* __restrict__ ws3, float* __restrict__ bf3)
{
    __shared__ u32 T[112 * 37];
    int tid = threadIdx.x;

    if (blockIdx.x < 448) {
        int pt0 = blockIdx.x % 7, b = blockIdx.x / 7;
        float inv_s0 = NBITF / r0[cluster[0]];

        for (int i = tid; i < 112 * 8; i += 256) {      // zero kdw 24..31
            int row = i >> 3, c = 24 + (i & 7);
            T[row * 37 + c] = 0u;
        }
        for (int u = tid; u < 24 * 28; u += 256) {
            int pq = u % 28, icq = u / 28;
            int pxb = pt0 * 112 + pq * 4;
            int q[4][4];
            #pragma unroll
            for (int j = 0; j < 4; j++) {
                v4f xv = *(const v4f*)(x + ((size_t)b * CIN + icq * 4 + j) * P_ + pxb);
                #pragma unroll
                for (int i = 0; i < 4; i++)
                    q[j][i] = (int)fminf(fmaxf(rintf(xv[i] * inv_s0), -127.f), 127.f);
            }
            #pragma unroll
            for (int i = 0; i < 4; i++) {
                u32 t0 = __builtin_amdgcn_perm((u32)q[1][i], (u32)q[0][i], 0x00000400u);
                u32 t1 = __builtin_amdgcn_perm((u32)q[3][i], (u32)q[2][i], 0x00000400u);
                T[(pq * 4 + i) * 37 + icq] = __builtin_amdgcn_perm(t1, t0, 0x05040100u);
            }
        }
        __syncthreads();
        u32* gb = x8t2 + (size_t)b * XB4 * 4;
        for (int i = tid; i < 32 * 112; i += 256) {
            int icq = i / 112, pxo = i - icq * 112;
            int px = pt0 * 112 + pxo;
            gb[(((px >> 6) * 8 + (icq >> 2)) * 64 + (px & 63)) * 4 + (icq & 3)] =
                T[pxo * 37 + icq];
        }
        return;
    }

    int lane = tid & 63, wv = tid >> 6;
    int blk = (blockIdx.x - 448) * 4 + wv;   // 0..1247

    const float *w, *g, *bb, *mm, *vv;
    int oc, K, which;
    if (blk < CMID)            { which = 0; w = w1; g = g1; bb = b1; mm = m1; vv = v1; oc = blk;            K = CIN;  }
    else if (blk < 2 * CMID)   { which = 1; w = w2; g = g2; bb = b2; mm = m2; vv = v2; oc = blk - CMID;     K = 9;    }
    else                       { which = 2; w = w3; g = g3; bb = b3; mm = m3; vv = v3; oc = blk - 2 * CMID; K = CMID; }

    float scale = g[oc] / sqrtf(vv[oc] + EPSF);

    float mx = 0.f;
    for (int k = lane; k < K; k += 64)
        mx = fmaxf(mx, fabsf(w[oc * K + k] * scale));
    #pragma unroll
    for (int off = 1; off < 64; off <<= 1)
        mx = fmaxf(mx, __shfl_xor(mx, off));

    float s = mx / NBITF;

    int myq = 0;
    for (int k = lane; k < K; k += 64) {
        float wf = w[oc * K + k] * scale;
        float q  = fminf(fmaxf(rintf(wf / s), -127.f), 127.f);
        if (which == 0)      w1qp[oc * 144 + k] = (int8_t)q;
        else if (which == 1) myq = (int)q;
        else                 w3qp[oc * 592 + k] = (int8_t)q;
    }
    if (which == 0 && lane < 12)
        ((u32*)(w1qp + oc * 144))[24 + lane] = 0u;
    if (which == 1) {
        u32 qq[9];
        #pragma unroll
        for (int t = 0; t < 9; t++) qq[t] = (u32)__shfl(myq, t, 64) & 0xffu;
        if (lane == 0) {
            v4i pk;
            pk[0] = (int)(qq[0] | (qq[1] << 8) | (qq[2] << 16));
            pk[1] = (int)(qq[3] | (qq[4] << 8) | (qq[5] << 16));
            pk[2] = (int)(qq[6] | (qq[7] << 8) | (qq[8] << 16));
            pk[3] = 0;
            w2pk[oc] = pk;
        }
    }
    if (lane == 0) {
        float bf = bb[oc] - mm[oc] * scale;
        if (which == 0)      { ws1[oc] = s; bf1[oc] = bf; }
        else if (which == 1) { ws2[oc] = s; bf2[oc] = bf; }
        else                 { ws3[oc] = s; bf3[oc] = bf; }
    }
}

// ---------------------------------------------------------------------------
// conv12r: row-aligned fused conv1 + depthwise. Block = 192 oc x 2 out rows
// (window 4 rows = 112 px = 7 m-tiles). conv1 via swapped-operand int8 MFMA
// (A-frag = one dwordx4 from x8t2); y1 lives in LDS px-packed; depthwise
// slides along rows (3 ds_read/out-dword, no boundary selects); y2 transposed
// in-LDS (tr4) and stored as packed dwordx4 in ch-packed D-layout.
// Grid (3 mt x 14 rt, 64 b). LDS 33.8 KB. Two barriers.
// ---------------------------------------------------------------------------
__global__ __launch_bounds__(256)
void conv12r(const u32* __restrict__ x8t2, const int8_t* __restrict__ w1qp,
             const float* __restrict__ ws1, const float* __restrict__ bf1,
             const v4i* __restrict__ w2pk, const float* __restrict__ ws2,
             const float* __restrict__ bf2,
             const float* __restrict__ r0, const float* __restrict__ r1,
             const float* __restrict__ r2, const int* __restrict__ cluster,
             v4i* __restrict__ y2t)
{
    __shared__ u32 y1w[192 * 29];   // [chl][28 window dw + 1 pad]  22.3 KB
    __shared__ u32 y2s[192 * 15];   // [chl][14 out dw + 1 pad]     11.5 KB

    int tid = threadIdx.x, b = blockIdx.y;
    int mt = blockIdx.x / 14, rt = blockIdx.x - mt * 14;
    int R0 = 2 * rt;
    int W0 = (R0 - 1) * 28;          // window px base (may be -28)
    int lane = tid & 63, wv = tid >> 6;
    int n = lane & 15, q4 = lane >> 4;
    int ocw = mt * 192 + wv * 48;

    int   c      = cluster[0];
    float s0     = r0[c] / NBITF;
    float s1     = r1[c] / NBITF;
    float inv_s1 = NBITF / r1[c];
    float inv_s2 = NBITF / r2[c];
    int   u1i    = (int)fminf(rintf(6.f * inv_s1), 127.f);
    int   u2i    = (int)fminf(rintf(6.f * inv_s2), 127.f);

    // ---- conv1 MFMA over 7 m-tiles ----
    const v4i* xb = (const v4i*)x8t2 + (size_t)b * XB4;
    int pb[7];
    #pragma unroll
    for (int jm = 0; jm < 7; jm++) {
        int px = W0 + 16 * jm + n;
        px = min(max(px, 0), P_ - 1);
        pb[jm] = (px >> 6) * 512 + (px & 63);
    }

    v4i acc[3][7];
    #pragma unroll
    for (int jn = 0; jn < 3; jn++)
        #pragma unroll
        for (int jm = 0; jm < 7; jm++) acc[jn][jm] = (v4i){0, 0, 0, 0};

    const v4i* w4 = (const v4i*)w1qp;   // 9 v4i per oc
    #pragma unroll
    for (int ks = 0; ks < 2; ks++) {
        v4i bw[3];
        #pragma unroll
        for (int jn = 0; jn < 3; jn++)
            bw[jn] = w4[(ocw + 16 * jn + n) * 9 + 4 * ks + q4];
        int go = (4 * ks + q4) * 64;
        #pragma unroll
        for (int jm = 0; jm < 7; jm++) {
            v4i af = xb[pb[jm] + go];
            #pragma unroll
            for (int jn = 0; jn < 3; jn++)
                acc[jn][jm] = __builtin_amdgcn_mfma_i32_16x16x64_i8(af, bw[jn], acc[jn][jm], 0, 0, 0);
        }
    }

    // ---- epilogue 1: quant(relu6) -> px-packed dwords in y1w ----
    #pragma unroll
    for (int jn = 0; jn < 3; jn++) {
        int   oc  = ocw + 16 * jn + n;
        int   chl = wv * 48 + 16 * jn + n;
        float scv = s0 * ws1[oc] * inv_s1;
        float bbv = bf1[oc] * inv_s1;
        #pragma unroll
        for (int jm = 0; jm < 7; jm++) {
            u32 t[4];
            #pragma unroll
            for (int r = 0; r < 4; r++) {
                float f = fmaf((float)acc[jn][jm][r], scv, bbv) + MAGICF;
                t[r] = (u32)min(max(__float_as_int(f), BIASI), BIASI + u1i);
            }
            int dw = 4 * jm + q4;                       // 0..27
            u32 pk = pack4(t[0], t[1], t[2], t[3]);
            pk = ((unsigned)(W0 + 4 * dw) < (unsigned)P_) ? pk : 0u;
            y1w[chl * 29 + dw] = pk;
        }
    }
    __syncthreads();

    // ---- depthwise 3x3, sliding along rows; write y2s px-packed ----
    for (int u = tid; u < 384; u += 256) {
        int chl = u >> 1, orow = u & 1;
        int ch  = mt * 192 + chl;
        int rb  = chl * 29 + orow * 7;

        v4i wpk = w2pk[ch];
        u32 pk0 = (u32)wpk[0], pk1 = (u32)wpk[1], pk2 = (u32)wpk[2];
        float scv = s1 * ws2[ch] * inv_s2;
        float bbv = bf2[ch] * inv_s2;

        u32 M0 = 0, M1 = 0, M2 = 0;
        u32 D0 = y1w[rb], D1 = y1w[rb + 7], D2 = y1w[rb + 14];
        #pragma unroll
        for (int xq = 0; xq < 7; xq++) {
            u32 N0, N1, N2;
            if (xq < 6) {
                N0 = y1w[rb + xq + 1];
                N1 = y1w[rb + 7 + xq + 1];
                N2 = y1w[rb + 14 + xq + 1];
            } else { N0 = N1 = N2 = 0u; }

            int a0, a1, a2, a3;
            a0 = dot3(__builtin_amdgcn_alignbyte(D0, M0, 3), pk0, 0);
            a0 = dot3(__builtin_amdgcn_alignbyte(D1, M1, 3), pk1, a0);
            a0 = dot3(__builtin_amdgcn_alignbyte(D2, M2, 3), pk2, a0);
            a1 = dot3(D0, pk0, 0);
            a1 = dot3(D1, pk1, a1);
            a1 = dot3(D2, pk2, a1);
            a2 = dot3(__builtin_amdgcn_alignbyte(N0, D0, 1), pk0, 0);
            a2 = dot3(__builtin_amdgcn_alignbyte(N1, D1, 1), pk1, a2);
            a2 = dot3(__builtin_amdgcn_alignbyte(N2, D2, 1), pk2, a2);
            a3 = dot3(__builtin_amdgcn_alignbyte(N0, D0, 2), pk0, 0);
            a3 = dot3(__builtin_amdgcn_alignbyte(N1, D1, 2), pk1, a3);
            a3 = dot3(__builtin_amdgcn_alignbyte(N2, D2, 2), pk2, a3);

            int aa[4] = {a0, a1, a2, a3};
            u32 tq[4];
            #pragma unroll
            for (int i = 0; i < 4; i++) {
                float f = fmaf((float)aa[i], scv, bbv) + MAGICF;
                tq[i] = (u32)min(max(__float_as_int(f), BIASI), BIASI + u2i);
            }
            y2s[chl * 15 + orow * 7 + xq] = pack4(tq[0], tq[1], tq[2], tq[3]);

            M0 = D0; M1 = D1; M2 = D2;
            D0 = N0; D1 = N1; D2 = N2;
        }
    }
    __syncthreads();

    // ---- tr4 + packed dwordx4 store into ch-packed D-layout ----
    v4i* yb = y2t + (size_t)b * YB4;
    for (int u = tid; u < 168; u += 256) {
        int kgl = u / 14, d = u - kgl * 14;     // kgl 0..11, d 0..13
        u32 O[4][4];
        #pragma unroll
        for (int j = 0; j < 4; j++) {
            int cb = (16 * kgl + 4 * j) * 15 + d;
            tr4(y2s[cb], y2s[cb + 15], y2s[cb + 30], y2s[cb + 45], O[j]);
        }
        int gpx0 = R0 * 28 + 4 * d;
        #pragma unroll
        for (int i = 0; i < 4; i++) {
            int gp = gpx0 + i;
            v4i val = (v4i){(int)O[0][i], (int)O[1][i], (int)O[2][i], (int)O[3][i]};
            yb[((gp >> 6) * 36 + mt * 12 + kgl) * 64 + (gp & 63)] = val;
        }
    }
}

// ---------------------------------------------------------------------------
// conv3d: 1x1 projection 576->96, LDS-free. B-frags = single dwordx4 from
// y2t D-layout; A-frags = dwordx4 from w3qp (L2). Fused residual + requant.
// Grid (13 pt, 64 b); block 256 = 4 waves x 16 px.
// ---------------------------------------------------------------------------
__global__ __launch_bounds__(256)
void conv3d(const v4i* __restrict__ y2t, const int8_t* __restrict__ w3qp,
            const float* __restrict__ ws3, const float* __restrict__ bf3,
            const float* __restrict__ x, const float* __restrict__ r2,
            const float* __restrict__ r3, const int* __restrict__ cluster,
            float* __restrict__ out)
{
    int tid = threadIdx.x, b = blockIdx.y, pt = blockIdx.x;
    int lane = tid & 63, wv = tid >> 6;
    int n = lane & 15, q4 = lane >> 4;
    int pxl = wv * 16 + n;
    int px  = pt * 64 + pxl;
    int pxc = min(px, P_ - 1);

    int   c      = cluster[0];
    float s2     = r2[c] / NBITF;
    float s3     = r3[c] / NBITF;
    float inv_s3 = NBITF / r3[c];

    const v4i* yb  = y2t + (size_t)b * YB4;
    int pb3 = (pxc >> 6) * (36 * 64) + (pxc & 63);
    const v4i* w34 = (const v4i*)w3qp;   // 37 v4i per oc row

    v4i acc[6];
    #pragma unroll
    for (int i = 0; i < 6; i++) acc[i] = (v4i){0, 0, 0, 0};

    #pragma unroll
    for (int ks = 0; ks < 9; ks++) {
        v4i bfr = yb[pb3 + (4 * ks + q4) * 64];
        #pragma unroll
        for (int i = 0; i < 6; i++) {
            v4i afr = w34[(i * 16 + n) * 37 + 4 * ks + q4];
            acc[i] = __builtin_amdgcn_mfma_i32_16x16x64_i8(afr, bfr, acc[i], 0, 0, 0);
        }
    }

    if (px < P_) {
        #pragma unroll
        for (int i = 0; i < 6; i++) {
            #pragma unroll
            for (int r = 0; r < 4; r++) {
                int oc = i * 16 + q4 * 4 + r;
                size_t gi = (size_t)(b * COUT + oc) * P_ + px;
                float v  = (float)acc[i][r] * (s2 * ws3[oc]) + bf3[oc] + x[gi];
                float f  = fmaf(v, inv_s3, MAGICF);
                int lvl  = min(max(__float_as_int(f) - BIASI, -127), 127);
                out[gi]  = (float)lvl * s3;
            }
        }
    }
    if (pt == 0 && b == 0 && tid == 0)
        out[NOUT] = s3;
}

// ---------------------------------------------------------------------------
extern "C" void kernel_launch(void* const* d_in, const int* in_sizes, int n_in,
                              void* d_out, int out_size, void* d_ws, size_t ws_size,
                              hipStream_t stream)
{
    const float* x  = (const float*)d_in[0];
    const float* w1 = (const float*)d_in[1];
    const float* g1 = (const float*)d_in[2];
    const float* b1 = (const float*)d_in[3];
    const float* m1 = (const float*)d_in[4];
    const float* v1 = (const float*)d_in[5];
    const float* w2 = (const float*)d_in[6];
    const float* g2 = (const float*)d_in[7];
    const float* b2 = (const float*)d_in[8];
    const float* m2 = (const float*)d_in[9];
    const float* v2 = (const float*)d_in[10];
    const float* w3 = (const float*)d_in[11];
    const float* g3 = (const float*)d_in[12];
    const float* b3 = (const float*)d_in[13];
    const float* m3 = (const float*)d_in[14];
    const float* v3 = (const float*)d_in[15];
    const float* r0 = (const float*)d_in[16];
    const float* r1 = (const float*)d_in[17];
    const float* r2 = (const float*)d_in[18];
    const float* r3 = (const float*)d_in[19];
    const int*   cl = (const int*)d_in[20];

    float* out = (float*)d_out;

    char*  ws  = (char*)d_ws;
    size_t off = 0;
    auto carve = [&](size_t bytes) {
        size_t cur = off;
        off = (off + bytes + 255) & ~(size_t)255;
        return (void*)(ws + cur);
    };
    int8_t* w1qp = (int8_t*)carve((size_t)CMID * 144);
    float*  ws1  = (float*)carve(CMID * 4);
    float*  bf1  = (float*)carve(CMID * 4);
    v4i*    w2pk = (v4i*)carve((size_t)CMID * 16);
    float*  ws2  = (float*)carve(CMID * 4);
    float*  bf2  = (float*)carve(CMID * 4);
    int8_t* w3qp = (int8_t*)carve((size_t)COUT * 592);
    float*  ws3  = (float*)carve(COUT * 4);
    float*  bf3  = (float*)carve(COUT * 4);
    u32*    x8t2 = (u32*)carve((size_t)B_ * XB4 * 16);   // 6.8 MB
    v4i*    y2t  = (v4i*)carve((size_t)B_ * YB4 * 16);   // 30.7 MB
    (void)ws_size; (void)in_sizes; (void)n_in; (void)out_size;

    prep_all<<<dim3(760), dim3(256), 0, stream>>>(
        x, w1, g1, b1, m1, v1, w2, g2, b2, m2, v2, w3, g3, b3, m3, v3,
        r0, cl, x8t2,
        w1qp, ws1, bf1, w2pk, ws2, bf2, w3qp, ws3, bf3);

    conv12r<<<dim3(42, B_), dim3(256), 0, stream>>>(
        x8t2, w1qp, ws1, bf1, w2pk, ws2, bf2, r0, r1, r2, cl, y2t);

    conv3d<<<dim3(13, B_), dim3(256), 0, stream>>>(
        y2t, w3qp, ws3, bf3, x, r2, r3, cl, out);
}